// Round 4
// baseline (1068.182 us; speedup 1.0000x reference)
//
#include <hip/hip_runtime.h>

typedef __bf16 bf16_t;
typedef bf16_t bf16x8 __attribute__((ext_vector_type(8)));
typedef bf16_t bf16x4 __attribute__((ext_vector_type(4)));
typedef float floatx4 __attribute__((ext_vector_type(4)));

#define T_TOKENS 8192
#define HIDDEN 1024
#define FFN 4096
#define NE 8
#define PAIRS 16384     // T_TOKENS * TOP_K
#define NT256 72        // max 256-row tiles: PAIRS/256 + NE partials
#define BK 64

// async global->LDS, 16B per lane; LDS dest is wave-uniform base + lane*16
#define GLD16(gp, lp) __builtin_amdgcn_global_load_lds( \
    (const __attribute__((address_space(1))) void*)(gp), \
    (__attribute__((address_space(3))) void*)(lp), 16, 0, 0)

// ---- stage half-tile h (128 rows) of tile t_ into buffer b (2 GLD16/thread)
// A lives at SH[b*16384 ..], B at SH[32768 + b*16384 ..]; row stride 64 bf16.
// TAIL FIX (round 3 bug): index is CLAMPED, never skipped, so the number of
// outstanding vmem ops is uniform (8/tile) and vmcnt(6) at phase 0 always
// implies the current tile's 4 half-tiles have landed. Clamped dummy loads
// read valid memory and land in a buffer that is never consumed.
#define ST_A(b, h, t_) do { \
    const size_t tb_ = (size_t)(((t_) < NKT) ? (t_) : (NKT - 1)) * 128; \
    GLD16(baseA + (size_t)voffA[(h)*2+0] + tb_, \
          SH + (b)*16384 + ((h)*128 +  0 + w8)*64); \
    GLD16(baseA + (size_t)voffA[(h)*2+1] + tb_, \
          SH + (b)*16384 + ((h)*128 + 64 + w8)*64); \
} while (0)
#define ST_B(b, h, t_) do { \
    const size_t tb_ = (size_t)(((t_) < NKT) ? (t_) : (NKT - 1)) * 128; \
    GLD16(baseB + (size_t)voffB[(h)*2+0] + tb_, \
          SH + 32768 + (b)*16384 + ((h)*128 +  0 + w8)*64); \
    GLD16(baseB + (size_t)voffB[(h)*2+1] + tb_, \
          SH + 32768 + (b)*16384 + ((h)*128 + 64 + w8)*64); \
} while (0)

// ---- fragment ds_reads (XOR-swizzled granules, verified rounds 1-2)
#define RDA(mi, h, coff) af[mi][h] = *(const bf16x8*)(SH + (coff) + \
    (wm*128 + (mi)*16 + lrow)*64 + ((((h)<<2)|quad) ^ lsw)*8)
#define RDB(ni, h, coff) bfr[ni][h] = *(const bf16x8*)(SH + 32768 + (coff) + \
    (wn*64 + (ni)*16 + lrow)*64 + ((((h)<<2)|quad) ^ lsw)*8)

#define MM1(mi, ni, h) acc[mi][ni] = __builtin_amdgcn_mfma_f32_16x16x32_bf16( \
    af[mi][h], bfr[ni][h], acc[mi][ni], 0, 0, 0)
#define MM4x2(mb, nb) do { \
    MM1(mb+0, nb+0, 0); MM1(mb+0, nb+1, 0); MM1(mb+1, nb+0, 0); MM1(mb+1, nb+1, 0); \
    MM1(mb+2, nb+0, 0); MM1(mb+2, nb+1, 0); MM1(mb+3, nb+0, 0); MM1(mb+3, nb+1, 0); \
    MM1(mb+0, nb+0, 1); MM1(mb+0, nb+1, 1); MM1(mb+1, nb+0, 1); MM1(mb+1, nb+1, 1); \
    MM1(mb+2, nb+0, 1); MM1(mb+2, nb+1, 1); MM1(mb+3, nb+0, 1); MM1(mb+3, nb+1, 1); \
} while (0)

// ---- one K-tile: 3 phases, counted vmcnt(6) (never 0), barrier per phase.
// Slot schedule (stage dist +7 half-tiles): ph0 stages A1(t+1) [occupant last
// read ph1(t-1)]; ph1 stages B0(t+2) [B fully read at ph0(t)]; ph2 stages
// A0(t+2)+B1(t+2) [A0 read thru ph0(t), B1 read at ph0(t)]. Every overwrite is
// >=1 barrier after the occupant's last ds_read; with uniform staging (clamp),
// vmcnt(6) at ph0 guarantees tile t's 4 half-tiles landed (only the 3 newest
// half-tiles, belonging to tiles t+1/t+2, may remain in flight).
#define TILE_PHASES(t_, cur, nxt) do { \
    asm volatile("s_waitcnt vmcnt(6)" ::: "memory"); \
    __builtin_amdgcn_s_barrier(); \
    asm volatile("" ::: "memory"); \
    { const int coff = (cur)*16384; \
      RDA(0,0,coff); RDA(0,1,coff); RDA(1,0,coff); RDA(1,1,coff); \
      RDA(2,0,coff); RDA(2,1,coff); RDA(3,0,coff); RDA(3,1,coff); \
      RDB(0,0,coff); RDB(0,1,coff); RDB(1,0,coff); RDB(1,1,coff); \
      RDB(2,0,coff); RDB(2,1,coff); RDB(3,0,coff); RDB(3,1,coff); } \
    ST_A(nxt, 1, (t_)+1); \
    asm volatile("s_waitcnt lgkmcnt(0)" ::: "memory"); \
    __builtin_amdgcn_sched_barrier(0); \
    __builtin_amdgcn_s_setprio(1); \
    MM4x2(0, 0); \
    __builtin_amdgcn_s_setprio(0); \
    __builtin_amdgcn_s_barrier(); \
    asm volatile("" ::: "memory"); \
    { const int coff = (cur)*16384; \
      RDA(4,0,coff); RDA(4,1,coff); RDA(5,0,coff); RDA(5,1,coff); \
      RDA(6,0,coff); RDA(6,1,coff); RDA(7,0,coff); RDA(7,1,coff); } \
    ST_B(cur, 0, (t_)+2); \
    asm volatile("s_waitcnt lgkmcnt(0)" ::: "memory"); \
    __builtin_amdgcn_sched_barrier(0); \
    __builtin_amdgcn_s_setprio(1); \
    MM4x2(0, 2); \
    __builtin_amdgcn_s_setprio(0); \
    __builtin_amdgcn_s_barrier(); \
    asm volatile("" ::: "memory"); \
    ST_A(cur, 0, (t_)+2); \
    ST_B(cur, 1, (t_)+2); \
    __builtin_amdgcn_s_setprio(1); \
    MM4x2(4, 0); MM4x2(4, 2); \
    __builtin_amdgcn_s_setprio(0); \
} while (0)

// common per-thread geometry for the 256x256 GEMM blocks
#define GEMM_GEOM() \
    const int tid  = threadIdx.x; \
    const int wid  = tid >> 6, lane = tid & 63; \
    const int wm   = wid >> 2, wn   = wid & 3; \
    const int quad = lane >> 4, lrow = lane & 15; \
    const int lsw  = lrow & 7; \
    const int w8   = wid * 8; \
    const int row8 = tid >> 3; \
    const int gs   = (tid & 7) ^ (row8 & 7)

// ------------------------------------------- gate + top2 (+ fused x->bf16)
__global__ __launch_bounds__(256) void gate_kernel(
    const float* __restrict__ x, const float* __restrict__ gw,
    const float* __restrict__ gb, unsigned* __restrict__ top2,
    int* __restrict__ counts, bf16_t* __restrict__ xb)
{
    const int lane = threadIdx.x & 63;
    const int wid  = threadIdx.x >> 6;
    const int t    = blockIdx.x * 4 + wid;
    const float4* xr = (const float4*)(x + (size_t)t * HIDDEN);
    bf16_t* xo = xb + (size_t)t * HIDDEN;

    float s[NE];
#pragma unroll
    for (int e = 0; e < NE; ++e) s[e] = 0.f;
#pragma unroll
    for (int ii = 0; ii < 4; ++ii) {
        const int i = ii * 64 + lane;
        float4 v = xr[i];
        bf16x4 b;
        b[0] = (bf16_t)v.x; b[1] = (bf16_t)v.y; b[2] = (bf16_t)v.z; b[3] = (bf16_t)v.w;
        *(bf16x4*)(xo + i * 4) = b;
        const float* g = gw + (size_t)i * 32;
#pragma unroll
        for (int j = 0; j < 4; ++j) {
            const float xv = (&v.x)[j];
#pragma unroll
            for (int e = 0; e < NE; ++e) s[e] += xv * g[j * 8 + e];
        }
    }
#pragma unroll
    for (int e = 0; e < NE; ++e) {
#pragma unroll
        for (int off = 32; off > 0; off >>= 1) s[e] += __shfl_xor(s[e], off, 64);
    }
    if (lane == 0) {
        float v1 = -1e30f, v2 = -1e30f;
        int i1 = 0, i2 = 0;
#pragma unroll
        for (int e = 0; e < NE; ++e) {
            float v = s[e] + gb[e];
            if (v > v1)      { v2 = v1; i2 = i1; v1 = v; i1 = e; }
            else if (v > v2) { v2 = v;  i2 = e; }
        }
        top2[t] = (unsigned)(i1 | (i2 << 4));
        atomicAdd(&counts[i1], 1);
        atomicAdd(&counts[i2], 1);
    }
}

// ------------------------- prefix offsets + 256-row tile table
__global__ void offsets_kernel(const int* __restrict__ counts,
                               int* __restrict__ offs,
                               int* __restrict__ tinfo)
{
    int acc = 0, nt = 0;
    for (int e = 0; e < NE; ++e) {
        offs[e] = acc;
        int n = counts[e];
        for (int r = 0; r < n; r += 256) tinfo[nt++] = e | ((r >> 8) << 4);
        acc += n;
    }
    for (; nt < NT256; ++nt) tinfo[nt] = (65535 << 4);  // row0 huge -> block exits
}

// ----------------------- scatter: token lists (u16)
__global__ __launch_bounds__(256) void scatter_kernel(
    const unsigned* __restrict__ top2, const int* __restrict__ offs,
    int* __restrict__ fill, unsigned short* __restrict__ tok16)
{
    const int t = blockIdx.x * 256 + threadIdx.x;
    const unsigned v = top2[t];
    const int e1 = v & 15, e2 = (v >> 4) & 15;
    tok16[offs[e1] + atomicAdd(&fill[e1], 1)] = (unsigned short)t;
    tok16[offs[e2] + atomicAdd(&fill[e2], 1)] = (unsigned short)t;
}

// ------------------------------- fp32 [E][R][C] -> bf16 [E][C][R] transpose
__global__ __launch_bounds__(256) void wtrans_kernel(
    const float* __restrict__ in, bf16_t* __restrict__ out, int R, int C)
{
    __shared__ bf16_t L[64][68];
    const int e  = blockIdx.z;
    const int r0 = blockIdx.y * 64;
    const int c0 = blockIdx.x * 64;
    const float* ip = in + ((size_t)e * R + r0) * C + c0;
    bf16_t* op = out + ((size_t)e * C + c0) * R + r0;
    const int tid = threadIdx.x;
    const int lr = tid >> 4, lc4 = tid & 15;
#pragma unroll
    for (int p = 0; p < 4; ++p) {
        int r = p * 16 + lr;
        float4 v = *(const float4*)(ip + (size_t)r * C + lc4 * 4);
        bf16x4 b;
        b[0] = (bf16_t)v.x; b[1] = (bf16_t)v.y; b[2] = (bf16_t)v.z; b[3] = (bf16_t)v.w;
        *(bf16x4*)&L[r][lc4 * 4] = b;
    }
    __syncthreads();
#pragma unroll
    for (int p = 0; p < 4; ++p) {
        int c  = p * 16 + lr;
        int rr = lc4 * 4;
        bf16x4 b;
        b[0] = L[rr + 0][c]; b[1] = L[rr + 1][c];
        b[2] = L[rr + 2][c]; b[3] = L[rr + 3][c];
        *(bf16x4*)(op + (size_t)c * R + rr) = b;
    }
}

// ------------------- GEMM1: 256x256 tile, 3-phase counted-vmcnt pipeline
// h1[slot][f] = relu(xb[tok[slot]] @ w1t[e]^T + b1[e])
__global__ __launch_bounds__(512, 2) void moe_gemm1(
    const bf16_t* __restrict__ xb, const bf16_t* __restrict__ w1t,
    const float* __restrict__ b1, const int* __restrict__ counts,
    const int* __restrict__ offs, const unsigned short* __restrict__ tok16,
    const int* __restrict__ tinfo, bf16_t* __restrict__ h1)
{
    __shared__ __align__(16) bf16_t SH[65536];   // 128 KB: A dbuf | B dbuf
    const int NKT = HIDDEN / BK;                 // 16

    // XCD-grouping swizzle (nwg = 16*72 = 1152, %8 == 0)
    const int nx = gridDim.x;
    const int hw = blockIdx.y * nx + blockIdx.x;
    const int chunk = (nx * gridDim.y) >> 3;
    const int l  = (hw & 7) * chunk + (hw >> 3);
    const int bx = l % nx;
    const int by = l / nx;

    const int info = tinfo[by];
    const int e    = info & 15;
    const int row0 = (info >> 4) << 8;
    const int n_e  = counts[e];
    if (row0 >= n_e) return;
    const int seg   = offs[e];
    const int fcol0 = bx * 256;

    GEMM_GEOM();

    // per-thread source byte-offsets (pre-swizzled granule gs)
    unsigned voffA[4], voffB[4];
#pragma unroll
    for (int j = 0; j < 4; ++j) {
        int rj = j * 64 + row8;
        int ridx = row0 + rj; if (ridx > n_e - 1) ridx = n_e - 1;
        voffA[j] = (unsigned)tok16[seg + ridx] * (HIDDEN * 2) + gs * 16;
        voffB[j] = (unsigned)(fcol0 + rj) * (HIDDEN * 2) + gs * 16;
    }
    const char* baseA = (const char*)xb;
    const char* baseB = (const char*)w1t + (size_t)e * FFN * HIDDEN * 2;

    floatx4 acc[8][4];
#pragma unroll
    for (int i = 0; i < 8; ++i)
#pragma unroll
        for (int j = 0; j < 4; ++j) acc[i][j] = (floatx4){0.f, 0.f, 0.f, 0.f};
    bf16x8 af[8][2], bfr[4][2];

    // prologue: 7 half-tiles (tile0 full + tile1 B0,A0,B1)
    ST_B(0, 0, 0); ST_A(0, 0, 0); ST_B(0, 1, 0); ST_A(0, 1, 0);
    ST_B(1, 0, 1); ST_A(1, 0, 1); ST_B(1, 1, 1);

    for (int t = 0; t < NKT; t += 2) {
        TILE_PHASES(t,     0, 1);
        TILE_PHASES(t + 1, 1, 0);
    }

    // epilogue: bias+relu -> swizzled LDS [256][256] bf16 -> 16B stores
    asm volatile("s_waitcnt vmcnt(0)" ::: "memory");
    __builtin_amdgcn_s_barrier();
    asm volatile("" ::: "memory");
    const float* b1g = b1 + (size_t)e * FFN + fcol0;
    float bias[4];
#pragma unroll
    for (int ni = 0; ni < 4; ++ni) bias[ni] = b1g[wn * 64 + ni * 16 + lrow];
#pragma unroll
    for (int mi = 0; mi < 8; ++mi)
#pragma unroll
        for (int ni = 0; ni < 4; ++ni) {
            const int col = wn * 64 + ni * 16 + lrow;
#pragma unroll
            for (int r = 0; r < 4; ++r) {
                int row = wm * 128 + mi * 16 + quad * 4 + r;
                float v = acc[mi][ni][r] + bias[ni];
                v = v > 0.f ? v : 0.f;
                SH[row * 256 + (col ^ ((row & 7) << 3))] = (bf16_t)v;
            }
        }
    __syncthreads();
#pragma unroll
    for (int i = 0; i < 16; ++i) {
        int gidx = i * 512 + tid;           // 8192 granules of 16B
        int row = gidx >> 5, g = gidx & 31;
        if (row0 + row < n_e)
            *(bf16x8*)(h1 + (size_t)(seg + row0 + row) * FFN + fcol0 + g * 8) =
                *(const bf16x8*)(SH + row * 256 + ((g * 8) ^ ((row & 7) << 3)));
    }
}

// --- GEMM2: 256x256 tile, split-K=2, 3-phase pipeline, fused atomic combine
__global__ __launch_bounds__(512, 2) void moe_gemm2(
    const bf16_t* __restrict__ h1, const bf16_t* __restrict__ w2t,
    const float* __restrict__ b2, const int* __restrict__ counts,
    const int* __restrict__ offs, const unsigned short* __restrict__ tok16,
    const int* __restrict__ tinfo, float* __restrict__ out)
{
    __shared__ __align__(16) bf16_t SH[65536];
    const int NKT = (FFN / 2) / BK;              // 32 per K-half

    // XCD-grouping swizzle (nwg = 8*72 = 576, %8 == 0)
    const int nx = gridDim.x;
    const int hw = blockIdx.y * nx + blockIdx.x;
    const int chunk = (nx * gridDim.y) >> 3;
    const int l  = (hw & 7) * chunk + (hw >> 3);
    const int bx = l % nx;
    const int by = l / nx;

    const int info = tinfo[by];
    const int e    = info & 15;
    const int row0 = (info >> 4) << 8;
    const int n_e  = counts[e];
    if (row0 >= n_e) return;
    const int seg   = offs[e];
    const int hcol0 = (bx & 3) * 256;
    const int kh    = bx >> 2;

    GEMM_GEOM();

    unsigned voffA[4], voffB[4];
#pragma unroll
    for (int j = 0; j < 4; ++j) {
        int rj = j * 64 + row8;
        int ridx = row0 + rj; if (ridx > n_e - 1) ridx = n_e - 1;
        voffA[j] = (unsigned)(seg + ridx) * (FFN * 2) + gs * 16;
        voffB[j] = (unsigned)(hcol0 + rj) * (FFN * 2) + gs * 16;
    }
    const char* baseA = (const char*)h1 + (size_t)kh * (FFN / 2) * 2;
    const char* baseB = (const char*)w2t + (size_t)e * HIDDEN * FFN * 2
                        + (size_t)kh * (FFN / 2) * 2;

    floatx4 acc[8][4];
#pragma unroll
    for (int i = 0; i < 8; ++i)
#pragma unroll
        for (int j = 0; j < 4; ++j) acc[i][j] = (floatx4){0.f, 0.f, 0.f, 0.f};
    bf16x8 af[8][2], bfr[4][2];

    ST_B(0, 0, 0); ST_A(0, 0, 0); ST_B(0, 1, 0); ST_A(0, 1, 0);
    ST_B(1, 0, 1); ST_A(1, 0, 1); ST_B(1, 1, 1);

    for (int t = 0; t < NKT; t += 2) {
        TILE_PHASES(t,     0, 1);
        TILE_PHASES(t + 1, 1, 0);
    }

    // drain in-flight global_load_lds before block exit (LDS realloc hazard)
    asm volatile("s_waitcnt vmcnt(0)" ::: "memory");

    // fused combine: out[tok] += acc (+ b2 once, at kh==0)
    const float* b2g = b2 + (size_t)e * HIDDEN + hcol0;
    float bias[4];
#pragma unroll
    for (int ni = 0; ni < 4; ++ni)
        bias[ni] = (kh == 0) ? b2g[wn * 64 + ni * 16 + lrow] : 0.f;
#pragma unroll
    for (int mi = 0; mi < 8; ++mi)
#pragma unroll
        for (int r = 0; r < 4; ++r) {
            int row = wm * 128 + mi * 16 + quad * 4 + r;
            if (row0 + row < n_e) {
                int tok = tok16[seg + row0 + row];
                float* op = out + (size_t)tok * HIDDEN + hcol0;
#pragma unroll
                for (int ni = 0; ni < 4; ++ni)
                    atomicAdd(op + wn * 64 + ni * 16 + lrow,
                              acc[mi][ni][r] + bias[ni]);
            }
        }
}

// -------------------------------------------------------------------- launch
extern "C" void kernel_launch(void* const* d_in, const int* in_sizes, int n_in,
                              void* d_out, int out_size, void* d_ws, size_t ws_size,
                              hipStream_t stream)
{
    const float* x      = (const float*)d_in[0];
    const float* gate_w = (const float*)d_in[1];
    const float* gate_b = (const float*)d_in[2];
    const float* w1     = (const float*)d_in[3];
    const float* b1     = (const float*)d_in[4];
    const float* w2     = (const float*)d_in[5];
    const float* b2     = (const float*)d_in[6];
    float* out = (float*)d_out;

    char* ws = (char*)d_ws;
    int*      counts = (int*)(ws + 0);       // 32 B
    int*      fill   = (int*)(ws + 32);      // 32 B
    int*      offs   = (int*)(ws + 64);      // 32 B
    int*      tinfo  = (int*)(ws + 96);      // 72*4 = 288 B (within 640)
    unsigned* top2   = (unsigned*)(ws + 640);                     // 32 KB
    unsigned short* tok16 = (unsigned short*)(ws + 640 + 32768);  // 32 KB
    const size_t o_base = 98560;

    const size_t sz_xb  = (size_t)T_TOKENS * HIDDEN * 2;   // 16 MB
    const size_t sz_w1t = (size_t)NE * FFN * HIDDEN * 2;   // 64 MB
    const size_t sz_w2t = (size_t)NE * HIDDEN * FFN * 2;   // 64 MB
    const size_t sz_h1  = (size_t)PAIRS * FFN * 2;         // 128 MB
    const size_t need = o_base + sz_xb + sz_w1t + sz_w2t + sz_h1;
    if (ws_size < need) return;

    bf16_t* xb  = (bf16_t*)(ws + o_base);
    bf16_t* w1t = (bf16_t*)(ws + o_base + sz_xb);
    bf16_t* w2t = (bf16_t*)(ws + o_base + sz_xb + sz_w1t);
    bf16_t* h1  = (bf16_t*)(ws + o_base + sz_xb + sz_w1t + sz_w2t);

    hipMemsetAsync(ws, 0, 96, stream);  // counts/fill/offs
    hipMemsetAsync(out, 0, (size_t)T_TOKENS * HIDDEN * sizeof(float), stream);

    gate_kernel<<<T_TOKENS / 4, 256, 0, stream>>>(x, gate_w, gate_b, top2, counts, xb);
    offsets_kernel<<<1, 1, 0, stream>>>(counts, offs, tinfo);
    scatter_kernel<<<T_TOKENS / 256, 256, 0, stream>>>(top2, offs, fill, tok16);

    wtrans_kernel<<<dim3(FFN / 64, HIDDEN / 64, NE), 256, 0, stream>>>(w1, w1t, HIDDEN, FFN);
    wtrans_kernel<<<dim3(HIDDEN / 64, FFN / 64, NE), 256, 0, stream>>>(w2, w2t, FFN, HIDDEN);

    moe_gemm1<<<dim3(FFN / 256, NT256), 512, 0, stream>>>(
        xb, w1t, b1, counts, offs, tok16, tinfo, h1);
    moe_gemm2<<<dim3((HIDDEN / 256) * 2, NT256), 512, 0, stream>>>(
        h1, w2t, b2, counts, offs, tok16, tinfo, out);
}

// Round 5
// 1056.824 us; speedup vs baseline: 1.0107x; 1.0107x over previous
//
#include <hip/hip_runtime.h>

typedef __bf16 bf16_t;
typedef bf16_t bf16x8 __attribute__((ext_vector_type(8)));
typedef bf16_t bf16x4 __attribute__((ext_vector_type(4)));
typedef float floatx4 __attribute__((ext_vector_type(4)));

#define T_TOKENS 8192
#define HIDDEN 1024
#define FFN 4096
#define NE 8
#define PAIRS 16384     // T_TOKENS * TOP_K
#define NTILES 136      // max 128-row tiles: PAIRS/128 + NE partials
#define BK 32

// async global->LDS, 16B per lane; LDS dest is wave-uniform base + lane*16
#define GLD16(gp, lp) __builtin_amdgcn_global_load_lds( \
    (const __attribute__((address_space(1))) void*)(gp), \
    (__attribute__((address_space(3))) void*)(lp), 16, 0, 0)

// ---- stage whole tile t_ (A 128x32 + B 128x32) into buffer at element
// offset bb (4 loads/thread). Source granule is pre-swizzled (gs), LDS dest
// linear (HW: uniform base + lane*16). Tail CLAMPED, never skipped, so the
// in-flight count is uniform (4/tile) and vmcnt(4) at the loop top always
// implies tile t landed (only tile t+1's 4 loads may remain outstanding).
#define STAGE(bb, t_) do { \
    const size_t tb_ = (size_t)(((t_) < NKT) ? (t_) : (NKT - 1)) * (BK * 2); \
    GLD16(baseA + (size_t)voffA0 + tb_, SH + (bb) + (wid * 64) * 8); \
    GLD16(baseA + (size_t)voffA1 + tb_, SH + (bb) + (256 + wid * 64) * 8); \
    GLD16(baseB + (size_t)voffB0 + tb_, SH + (bb) + 4096 + (wid * 64) * 8); \
    GLD16(baseB + (size_t)voffB1 + tb_, SH + (bb) + 4096 + (256 + wid * 64) * 8); \
} while (0)

// ---- one K-step: ONE barrier + counted vmcnt(4), 2-tile-deep prefetch.
// Buffer (t+2)%3 being overwritten was last ds_read at iter t-1, and those
// reads were retired by that iter's data-dependent lgkmcnt(0) BEFORE this
// iter's barrier -> single barrier is race-free with triple buffering.
#define KSTEP(t_, cb, sb) do { \
    asm volatile("s_waitcnt vmcnt(4)" ::: "memory"); \
    __builtin_amdgcn_s_barrier(); \
    asm volatile("" ::: "memory"); \
    bf16x8 af[4], bfr[4]; \
    _Pragma("unroll") \
    for (int mi = 0; mi < 4; ++mi) \
        af[mi] = *(const bf16x8*)&SH[(cb) + (wm * 64 + mi * 16 + lrow) * 32 + kx8]; \
    _Pragma("unroll") \
    for (int ni = 0; ni < 4; ++ni) \
        bfr[ni] = *(const bf16x8*)&SH[(cb) + 4096 + (wn * 64 + ni * 16 + lrow) * 32 + kx8]; \
    STAGE(sb, (t_) + 2); \
    asm volatile("s_waitcnt lgkmcnt(0)" ::: "memory"); \
    __builtin_amdgcn_sched_barrier(0); \
    __builtin_amdgcn_s_setprio(1); \
    _Pragma("unroll") \
    for (int mi = 0; mi < 4; ++mi) \
        _Pragma("unroll") \
        for (int ni = 0; ni < 4; ++ni) \
            acc[mi][ni] = __builtin_amdgcn_mfma_f32_16x16x32_bf16( \
                af[mi], bfr[ni], acc[mi][ni], 0, 0, 0); \
    __builtin_amdgcn_s_setprio(0); \
} while (0)

// common geometry: 256 threads, 4 waves in 2x2, per-wave 64x64 output
#define GEMM_GEOM() \
    const int tid  = threadIdx.x; \
    const int wid  = tid >> 6, lane = tid & 63; \
    const int wm   = wid & 1,  wn   = wid >> 1; \
    const int quad = lane >> 4, lrow = lane & 15; \
    const int kx8  = ((quad ^ (lrow & 3)) << 3)

// ------------------------------------------- gate + top2 (+ fused x->bf16)
__global__ __launch_bounds__(256) void gate_kernel(
    const float* __restrict__ x, const float* __restrict__ gw,
    const float* __restrict__ gb, unsigned* __restrict__ top2,
    int* __restrict__ counts, bf16_t* __restrict__ xb)
{
    const int lane = threadIdx.x & 63;
    const int wid  = threadIdx.x >> 6;
    const int t    = blockIdx.x * 4 + wid;
    const float4* xr = (const float4*)(x + (size_t)t * HIDDEN);
    bf16_t* xo = xb + (size_t)t * HIDDEN;

    float s[NE];
#pragma unroll
    for (int e = 0; e < NE; ++e) s[e] = 0.f;
#pragma unroll
    for (int ii = 0; ii < 4; ++ii) {
        const int i = ii * 64 + lane;
        float4 v = xr[i];
        bf16x4 b;
        b[0] = (bf16_t)v.x; b[1] = (bf16_t)v.y; b[2] = (bf16_t)v.z; b[3] = (bf16_t)v.w;
        *(bf16x4*)(xo + i * 4) = b;
        const float* g = gw + (size_t)i * 32;
#pragma unroll
        for (int j = 0; j < 4; ++j) {
            const float xv = (&v.x)[j];
#pragma unroll
            for (int e = 0; e < NE; ++e) s[e] += xv * g[j * 8 + e];
        }
    }
#pragma unroll
    for (int e = 0; e < NE; ++e) {
#pragma unroll
        for (int off = 32; off > 0; off >>= 1) s[e] += __shfl_xor(s[e], off, 64);
    }
    if (lane == 0) {
        float v1 = -1e30f, v2 = -1e30f;
        int i1 = 0, i2 = 0;
#pragma unroll
        for (int e = 0; e < NE; ++e) {
            float v = s[e] + gb[e];
            if (v > v1)      { v2 = v1; i2 = i1; v1 = v; i1 = e; }
            else if (v > v2) { v2 = v;  i2 = e; }
        }
        top2[t] = (unsigned)(i1 | (i2 << 4));
        atomicAdd(&counts[i1], 1);
        atomicAdd(&counts[i2], 1);
    }
}

// ------------------------- prefix offsets + 128-row tile table
__global__ void offsets_kernel(const int* __restrict__ counts,
                               int* __restrict__ offs,
                               int* __restrict__ tinfo)
{
    int acc = 0, nt = 0;
    for (int e = 0; e < NE; ++e) {
        offs[e] = acc;
        int n = counts[e];
        for (int r = 0; r < n; r += 128) tinfo[nt++] = e | ((r >> 7) << 4);
        acc += n;
    }
    for (; nt < NTILES; ++nt) tinfo[nt] = (65535 << 4);  // row0 huge -> block exits
}

// ----------------------- scatter: token lists (u16)
__global__ __launch_bounds__(256) void scatter_kernel(
    const unsigned* __restrict__ top2, const int* __restrict__ offs,
    int* __restrict__ fill, unsigned short* __restrict__ tok16)
{
    const int t = blockIdx.x * 256 + threadIdx.x;
    const unsigned v = top2[t];
    const int e1 = v & 15, e2 = (v >> 4) & 15;
    tok16[offs[e1] + atomicAdd(&fill[e1], 1)] = (unsigned short)t;
    tok16[offs[e2] + atomicAdd(&fill[e2], 1)] = (unsigned short)t;
}

// ---------- fp32 [E][R][C] -> bf16 [E][C][R] transpose, both weights, 1 launch
__global__ __launch_bounds__(256) void wtrans_kernel(
    const float* __restrict__ w1, bf16_t* __restrict__ w1t,
    const float* __restrict__ w2, bf16_t* __restrict__ w2t)
{
    __shared__ bf16_t L[64][68];
    const int bid = blockIdx.x;
    const int sel = bid >> 13;              // 0: w1 (1024x4096), 1: w2 (4096x1024)
    const int e   = (bid & 8191) >> 10;
    const int tl  = bid & 1023;
    const int R = sel ? FFN : HIDDEN;
    const int C = sel ? HIDDEN : FFN;
    const int cx = sel ? (tl & 15) : (tl & 63);
    const int ry = sel ? (tl >> 4) : (tl >> 6);
    const float* in = (sel ? w2 : w1);
    bf16_t* out = (sel ? w2t : w1t);
    const int r0 = ry * 64, c0 = cx * 64;
    const float* ip = in + ((size_t)e * R + r0) * C + c0;
    bf16_t* op = out + ((size_t)e * C + c0) * R + r0;
    const int tid = threadIdx.x;
    const int lr = tid >> 4, lc4 = tid & 15;
#pragma unroll
    for (int p = 0; p < 4; ++p) {
        int r = p * 16 + lr;
        float4 v = *(const float4*)(ip + (size_t)r * C + lc4 * 4);
        bf16x4 b;
        b[0] = (bf16_t)v.x; b[1] = (bf16_t)v.y; b[2] = (bf16_t)v.z; b[3] = (bf16_t)v.w;
        *(bf16x4*)&L[r][lc4 * 4] = b;
    }
    __syncthreads();
#pragma unroll
    for (int p = 0; p < 4; ++p) {
        int c  = p * 16 + lr;
        int rr = lc4 * 4;
        bf16x4 b;
        b[0] = L[rr + 0][c]; b[1] = L[rr + 1][c];
        b[2] = L[rr + 2][c]; b[3] = L[rr + 3][c];
        *(bf16x4*)(op + (size_t)c * R + rr) = b;
    }
}

// -------- GEMM1: 128x128, BK=32, triple-buffer, 1 barrier + vmcnt(4)/step
// h1[slot][f] = relu(xb[tok[slot]] @ w1t[e]^T + b1[e])
__global__ __launch_bounds__(256, 3) void moe_gemm1(
    const bf16_t* __restrict__ xb, const bf16_t* __restrict__ w1t,
    const float* __restrict__ b1, const int* __restrict__ counts,
    const int* __restrict__ offs, const unsigned short* __restrict__ tok16,
    const int* __restrict__ tinfo, bf16_t* __restrict__ h1)
{
    __shared__ __align__(16) bf16_t SH[24576];   // 3 x (A 4096 + B 4096) = 48 KB
    const int NKT = HIDDEN / BK;                 // 32

    // XCD-grouping swizzle (nwg = 32*136 = 4352, %8 == 0)
    const int nx = gridDim.x;
    const int hw = blockIdx.y * nx + blockIdx.x;
    const int chunk = (nx * gridDim.y) >> 3;
    const int l  = (hw & 7) * chunk + (hw >> 3);
    const int bx = l % nx;
    const int by = l / nx;

    const int info = tinfo[by];
    const int e    = info & 15;
    const int row0 = (info >> 4) << 7;
    const int n_e  = counts[e];
    if (row0 >= n_e) return;
    const int seg   = offs[e];
    const int fcol0 = bx * 128;

    GEMM_GEOM();

    // per-thread byte offsets; source granule gs pre-swizzled (gs = ko^(row&3))
    unsigned voffA0, voffA1, voffB0, voffB1;
    {
        int s0 = tid, s1 = 256 + tid;
        int a0 = s0 >> 2, a1 = s1 >> 2;
        int g0 = (s0 & 3) ^ (a0 & 3), g1 = (s1 & 3) ^ (a1 & 3);
        int r0i = row0 + a0; if (r0i > n_e - 1) r0i = n_e - 1;
        int r1i = row0 + a1; if (r1i > n_e - 1) r1i = n_e - 1;
        voffA0 = (unsigned)tok16[seg + r0i] * (HIDDEN * 2) + g0 * 16;
        voffA1 = (unsigned)tok16[seg + r1i] * (HIDDEN * 2) + g1 * 16;
        voffB0 = (unsigned)(fcol0 + a0) * (HIDDEN * 2) + g0 * 16;
        voffB1 = (unsigned)(fcol0 + a1) * (HIDDEN * 2) + g1 * 16;
    }
    const char* baseA = (const char*)xb;
    const char* baseB = (const char*)w1t + (size_t)e * FFN * HIDDEN * 2;

    floatx4 acc[4][4];
#pragma unroll
    for (int i = 0; i < 4; ++i)
#pragma unroll
        for (int j = 0; j < 4; ++j) acc[i][j] = (floatx4){0.f, 0.f, 0.f, 0.f};

    STAGE(0, 0);        // tile 0 -> buf0
    STAGE(8192, 1);     // tile 1 -> buf1
    int cb = 0, sb = 16384;
    for (int t = 0; t < NKT; ++t) {
        KSTEP(t, cb, sb);
        cb = (cb == 16384) ? 0 : cb + 8192;
        sb = (sb == 16384) ? 0 : sb + 8192;
    }

    // epilogue: drain, then bias+relu -> LDS [128][136] bf16 -> 16B stores
    asm volatile("s_waitcnt vmcnt(0)" ::: "memory");
    __builtin_amdgcn_s_barrier();
    asm volatile("" ::: "memory");
    const float* b1g = b1 + (size_t)e * FFN + fcol0;
    float bias[4];
#pragma unroll
    for (int ni = 0; ni < 4; ++ni) bias[ni] = b1g[wn * 64 + ni * 16 + lrow];
#pragma unroll
    for (int ni = 0; ni < 4; ++ni) {
        const int col = wn * 64 + ni * 16 + lrow;
#pragma unroll
        for (int mi = 0; mi < 4; ++mi)
#pragma unroll
            for (int r = 0; r < 4; ++r) {
                int row = wm * 64 + mi * 16 + quad * 4 + r;
                float v = acc[mi][ni][r] + bias[ni];
                v = v > 0.f ? v : 0.f;
                SH[row * 136 + col] = (bf16_t)v;
            }
    }
    __syncthreads();
#pragma unroll
    for (int i = 0; i < 8; ++i) {
        int g16 = i * 256 + tid;          // 2048 granules of 16B
        int row = g16 >> 4;
        int ce  = (g16 & 15) * 8;
        if (row0 + row < n_e)
            *(bf16x8*)(h1 + (size_t)(seg + row0 + row) * FFN + fcol0 + ce) =
                *(const bf16x8*)&SH[row * 136 + ce];
    }
}

// ---- GEMM2: 128x128, BK=32, triple-buffer, fused atomic combine into out
__global__ __launch_bounds__(256, 3) void moe_gemm2(
    const bf16_t* __restrict__ h1, const bf16_t* __restrict__ w2t,
    const float* __restrict__ b2, const int* __restrict__ counts,
    const int* __restrict__ offs, const unsigned short* __restrict__ tok16,
    const int* __restrict__ tinfo, float* __restrict__ out)
{
    __shared__ __align__(16) bf16_t SH[24576];
    const int NKT = FFN / BK;                    // 128

    // XCD-grouping swizzle (nwg = 8*136 = 1088, %8 == 0)
    const int nx = gridDim.x;
    const int hw = blockIdx.y * nx + blockIdx.x;
    const int chunk = (nx * gridDim.y) >> 3;
    const int l  = (hw & 7) * chunk + (hw >> 3);
    const int bx = l % nx;
    const int by = l / nx;

    const int info = tinfo[by];
    const int e    = info & 15;
    const int row0 = (info >> 4) << 7;
    const int n_e  = counts[e];
    if (row0 >= n_e) return;
    const int seg   = offs[e];
    const int hcol0 = bx * 128;

    GEMM_GEOM();

    unsigned voffA0, voffA1, voffB0, voffB1;
    {
        int s0 = tid, s1 = 256 + tid;
        int a0 = s0 >> 2, a1 = s1 >> 2;
        int g0 = (s0 & 3) ^ (a0 & 3), g1 = (s1 & 3) ^ (a1 & 3);
        int r0i = row0 + a0; if (r0i > n_e - 1) r0i = n_e - 1;
        int r1i = row0 + a1; if (r1i > n_e - 1) r1i = n_e - 1;
        voffA0 = (unsigned)(seg + r0i) * (FFN * 2) + g0 * 16;
        voffA1 = (unsigned)(seg + r1i) * (FFN * 2) + g1 * 16;
        voffB0 = (unsigned)(hcol0 + a0) * (FFN * 2) + g0 * 16;
        voffB1 = (unsigned)(hcol0 + a1) * (FFN * 2) + g1 * 16;
    }
    const char* baseA = (const char*)h1;
    const char* baseB = (const char*)w2t + (size_t)e * HIDDEN * FFN * 2;

    floatx4 acc[4][4];
#pragma unroll
    for (int i = 0; i < 4; ++i)
#pragma unroll
        for (int j = 0; j < 4; ++j) acc[i][j] = (floatx4){0.f, 0.f, 0.f, 0.f};

    STAGE(0, 0);
    STAGE(8192, 1);
    int cb = 0, sb = 16384;
    for (int t = 0; t < NKT; ++t) {
        KSTEP(t, cb, sb);
        cb = (cb == 16384) ? 0 : cb + 8192;
        sb = (sb == 16384) ? 0 : sb + 8192;
    }

    // drain in-flight global_load_lds before block exit (LDS realloc hazard)
    asm volatile("s_waitcnt vmcnt(0)" ::: "memory");

    // fused combine: out[tok] += acc + b2 (exactly 2 adds per element)
    int tokr[4][4];
#pragma unroll
    for (int mi = 0; mi < 4; ++mi)
#pragma unroll
        for (int r = 0; r < 4; ++r) {
            int row = wm * 64 + mi * 16 + quad * 4 + r;
            tokr[mi][r] = (row0 + row < n_e) ? (int)tok16[seg + row0 + row] : -1;
        }
#pragma unroll
    for (int ni = 0; ni < 4; ++ni) {
        const int col = wn * 64 + ni * 16 + lrow;
        const float bias = b2[(size_t)e * HIDDEN + hcol0 + col];
#pragma unroll
        for (int mi = 0; mi < 4; ++mi)
#pragma unroll
            for (int r = 0; r < 4; ++r) {
                if (tokr[mi][r] >= 0)
                    atomicAdd(out + (size_t)tokr[mi][r] * HIDDEN + hcol0 + col,
                              acc[mi][ni][r] + bias);
            }
    }
}

// -------------------------------------------------------------------- launch
extern "C" void kernel_launch(void* const* d_in, const int* in_sizes, int n_in,
                              void* d_out, int out_size, void* d_ws, size_t ws_size,
                              hipStream_t stream)
{
    const float* x      = (const float*)d_in[0];
    const float* gate_w = (const float*)d_in[1];
    const float* gate_b = (const float*)d_in[2];
    const float* w1     = (const float*)d_in[3];
    const float* b1     = (const float*)d_in[4];
    const float* w2     = (const float*)d_in[5];
    const float* b2     = (const float*)d_in[6];
    float* out = (float*)d_out;

    char* ws = (char*)d_ws;
    int*      counts = (int*)(ws + 0);       // 32 B
    int*      fill   = (int*)(ws + 32);      // 32 B
    int*      offs   = (int*)(ws + 64);      // 32 B
    int*      tinfo  = (int*)(ws + 96);      // 136*4 = 544 B -> 640
    unsigned* top2   = (unsigned*)(ws + 640);                     // 32 KB
    unsigned short* tok16 = (unsigned short*)(ws + 640 + 32768);  // 32 KB
    const size_t o_base = 98560;

    const size_t sz_xb  = (size_t)T_TOKENS * HIDDEN * 2;   // 16 MB
    const size_t sz_w1t = (size_t)NE * FFN * HIDDEN * 2;   // 64 MB
    const size_t sz_w2t = (size_t)NE * HIDDEN * FFN * 2;   // 64 MB
    const size_t sz_h1  = (size_t)PAIRS * FFN * 2;         // 128 MB
    const size_t need = o_base + sz_xb + sz_w1t + sz_w2t + sz_h1;
    if (ws_size < need) return;

    bf16_t* xb  = (bf16_t*)(ws + o_base);
    bf16_t* w1t = (bf16_t*)(ws + o_base + sz_xb);
    bf16_t* w2t = (bf16_t*)(ws + o_base + sz_xb + sz_w1t);
    bf16_t* h1  = (bf16_t*)(ws + o_base + sz_xb + sz_w1t + sz_w2t);

    hipMemsetAsync(ws, 0, 96, stream);  // counts/fill/offs
    hipMemsetAsync(out, 0, (size_t)T_TOKENS * HIDDEN * sizeof(float), stream);

    gate_kernel<<<T_TOKENS / 4, 256, 0, stream>>>(x, gate_w, gate_b, top2, counts, xb);
    offsets_kernel<<<1, 1, 0, stream>>>(counts, offs, tinfo);
    scatter_kernel<<<T_TOKENS / 256, 256, 0, stream>>>(top2, offs, fill, tok16);

    wtrans_kernel<<<16384, 256, 0, stream>>>(w1, w1t, w2, w2t);

    moe_gemm1<<<dim3(FFN / 128, NTILES), 256, 0, stream>>>(
        xb, w1t, b1, counts, offs, tok16, tinfo, h1);
    moe_gemm2<<<dim3(HIDDEN / 128, NTILES), 256, 0, stream>>>(
        h1, w2t, b2, counts, offs, tok16, tinfo, out);
}